// Round 1
// baseline (1059.998 us; speedup 1.0000x reference)
//
#include <hip/hip_runtime.h>

static constexpr int BTRIALS = 32;
static constexpr int TSTEPS  = 512;
static constexpr int IDIM    = 64;
static constexpr int NDIM    = 4096;
static constexpr int RDIM    = 8;
static constexpr int ODIM    = 64;

typedef short v8s __attribute__((ext_vector_type(8)));
typedef float v4f __attribute__((ext_vector_type(4)));

__device__ __forceinline__ float fast_sigmoid(float x) {
    float e = __builtin_amdgcn_exp2f(x * -1.44269504088896340736f);
    return __builtin_amdgcn_rcpf(1.0f + e);
}

// v += dpp_move(v), 0-fill invalid lanes
template <int CTRL, int RMASK>
__device__ __forceinline__ float dpp_add(float v) {
    int moved = __builtin_amdgcn_update_dpp(0, __float_as_int(v), CTRL, RMASK, 0xf, true);
    return v + __int_as_float(moved);
}

// full 64-lane sum -> valid in lane 63
__device__ __forceinline__ float wave_reduce_to_lane63(float v) {
    v = dpp_add<0x111, 0xf>(v);  // row_shr:1
    v = dpp_add<0x112, 0xf>(v);  // row_shr:2
    v = dpp_add<0x114, 0xf>(v);  // row_shr:4
    v = dpp_add<0x118, 0xf>(v);  // row_shr:8
    v = dpp_add<0x142, 0xa>(v);  // row_bcast:15 -> rows 1,3
    v = dpp_add<0x143, 0xc>(v);  // row_bcast:31 -> rows 2,3
    return v;
}

__device__ __forceinline__ short f2bf(float f) {
    unsigned u = __float_as_uint(f);
    u += 0x7FFFu + ((u >> 16) & 1u);   // RNE
    return (short)(u >> 16);
}

// ---------------------------------------------------------------------------
// Phase 1: u[t_local*32 + b][n] = DT * sum_i inp[b][t0+t_local][i] * B[n][i]
// (unchanged)
// ---------------------------------------------------------------------------
__global__ __launch_bounds__(256) void pre_gemm(const float* __restrict__ inp,
                                                const float* __restrict__ Bm,
                                                float* __restrict__ u,
                                                int t0, int rows) {
    __shared__ __align__(16) float At[64][68];
    __shared__ __align__(16) float Bt[64][68];
    const int tid = threadIdx.x;
    const int c4  = (tid & 15) * 4;
    const int rq  = tid >> 4;
    const int mbase = blockIdx.x * 64;
    const int nbase = blockIdx.y * 64;

    #pragma unroll
    for (int rr = 0; rr < 4; ++rr) {
        const int rloc = rr * 16 + rq;
        const int mr = mbase + rloc;
        float4 a = make_float4(0.f, 0.f, 0.f, 0.f);
        if (mr < rows) {
            const int b  = mr & 31;
            const int tl = mr >> 5;
            a = *(const float4*)(inp + ((size_t)b * TSTEPS + (t0 + tl)) * IDIM + c4);
        }
        At[c4 + 0][rloc] = a.x; At[c4 + 1][rloc] = a.y;
        At[c4 + 2][rloc] = a.z; At[c4 + 3][rloc] = a.w;
        const int n = nbase + rloc;
        float4 bb = *(const float4*)(Bm + (size_t)n * IDIM + c4);
        Bt[c4 + 0][rloc] = bb.x; Bt[c4 + 1][rloc] = bb.y;
        Bt[c4 + 2][rloc] = bb.z; Bt[c4 + 3][rloc] = bb.w;
    }
    __syncthreads();

    const int m4 = (tid >> 4) * 4;
    const int n4 = (tid & 15) * 4;
    float acc[4][4];
    #pragma unroll
    for (int i = 0; i < 4; ++i)
        #pragma unroll
        for (int j = 0; j < 4; ++j) acc[i][j] = 0.f;

    #pragma unroll 8
    for (int k = 0; k < 64; ++k) {
        float4 a = *(const float4*)&At[k][m4];
        float4 w = *(const float4*)&Bt[k][n4];
        float av[4] = {a.x, a.y, a.z, a.w};
        float wv[4] = {w.x, w.y, w.z, w.w};
        #pragma unroll
        for (int i = 0; i < 4; ++i)
            #pragma unroll
            for (int j = 0; j < 4; ++j)
                acc[i][j] = fmaf(av[i], wv[j], acc[i][j]);
    }

    #pragma unroll
    for (int i = 0; i < 4; ++i) {
        const int mr = mbase + m4 + i;
        if (mr < rows) {
            float4 o = make_float4(acc[i][0] * 0.1f, acc[i][1] * 0.1f,
                                   acc[i][2] * 0.1f, acc[i][3] * 0.1f);
            *(float4*)(u + (size_t)mr * NDIM + nbase + n4) = o;
        }
    }
}

// ---------------------------------------------------------------------------
// W fp32 -> bf16, once. [64][4096] row-major preserved.
// ---------------------------------------------------------------------------
__global__ __launch_bounds__(256) void wconv(const float* __restrict__ W,
                                             unsigned short* __restrict__ Wb) {
    const int base = (blockIdx.x * 256 + threadIdx.x) * 8;
    float4 a = *(const float4*)(W + base);
    float4 b = *(const float4*)(W + base + 4);
    v8s o;
    o[0] = f2bf(a.x); o[1] = f2bf(a.y); o[2] = f2bf(a.z); o[3] = f2bf(a.w);
    o[4] = f2bf(b.x); o[5] = f2bf(b.y); o[6] = f2bf(b.z); o[7] = f2bf(b.w);
    *(v8s*)(Wb + base) = o;
}

// ---------------------------------------------------------------------------
// Phase 2: serial scan. 32 blocks x 512 threads, 8 n/thread.
// Carries s = sigmoid(x) in registers; emits s as bf16 to sbuf (chunk-local
// layout [b][tl][n]) so y_gemm needs no sigmoid/f2bf and reads half the bytes.
// ---------------------------------------------------------------------------
__global__ __launch_bounds__(512, 2) void scan_kernel(const float* __restrict__ mmat,
                                                      const float* __restrict__ nmat,
                                                      const float* __restrict__ u,
                                                      float* __restrict__ xseq,
                                                      float* __restrict__ xstate,
                                                      unsigned short* __restrict__ sbuf,
                                                      int t0, int tc) {
    const int b    = blockIdx.x;
    const int tid  = threadIdx.x;
    const int j0   = tid * 8;
    const int lane = tid & 63;
    const int wv   = tid >> 6;   // 0..7

    __shared__ __align__(16) float wlds[2][64];   // [r*8 + w], double-buffered

    float nm[8][8], mmr[8][8], x[8], s[8];
    const float4* np4 = (const float4*)(nmat + (size_t)j0 * RDIM);
    const float4* mp4 = (const float4*)(mmat + (size_t)j0 * RDIM);
    const float mscale = 0.1f / 4096.0f;   // DT / N folded into m
    #pragma unroll
    for (int j = 0; j < 8; ++j) {
        float4 a = np4[j * 2], c = np4[j * 2 + 1];
        nm[j][0] = a.x; nm[j][1] = a.y; nm[j][2] = a.z; nm[j][3] = a.w;
        nm[j][4] = c.x; nm[j][5] = c.y; nm[j][6] = c.z; nm[j][7] = c.w;
        float4 d = mp4[j * 2], e = mp4[j * 2 + 1];
        mmr[j][0] = d.x * mscale; mmr[j][1] = d.y * mscale;
        mmr[j][2] = d.z * mscale; mmr[j][3] = d.w * mscale;
        mmr[j][4] = e.x * mscale; mmr[j][5] = e.y * mscale;
        mmr[j][6] = e.z * mscale; mmr[j][7] = e.w * mscale;
    }

    if (t0 == 0) {
        #pragma unroll
        for (int j = 0; j < 8; ++j) x[j] = 0.0f;
        float* z = xseq + (size_t)b * (TSTEPS + 1) * NDIM + j0;
        *(float4*)(z + 0) = make_float4(0.f, 0.f, 0.f, 0.f);
        *(float4*)(z + 4) = make_float4(0.f, 0.f, 0.f, 0.f);
    } else {
        const float* xs = xstate + (size_t)b * NDIM + j0;
        float4 v0 = *(const float4*)(xs + 0);
        float4 v1 = *(const float4*)(xs + 4);
        x[0] = v0.x; x[1] = v0.y; x[2] = v0.z; x[3] = v0.w;
        x[4] = v1.x; x[5] = v1.y; x[6] = v1.z; x[7] = v1.w;
    }
    #pragma unroll
    for (int j = 0; j < 8; ++j) s[j] = fast_sigmoid(x[j]);

    float uv[8];
    {
        const float* up = u + ((size_t)0 * BTRIALS + b) * NDIM + j0;
        float4 v0 = *(const float4*)(up + 0);
        float4 v1 = *(const float4*)(up + 4);
        uv[0] = v0.x; uv[1] = v0.y; uv[2] = v0.z; uv[3] = v0.w;
        uv[4] = v1.x; uv[5] = v1.y; uv[6] = v1.z; uv[7] = v1.w;
    }

    for (int tl = 0; tl < tc; ++tl) {
        const int buf = tl & 1;
        // prefetch u for next step
        const int tn = (tl + 1 < tc) ? (tl + 1) : tl;
        const float* upn = u + ((size_t)tn * BTRIALS + b) * NDIM + j0;
        float4 pf0 = *(const float4*)(upn + 0);
        float4 pf1 = *(const float4*)(upn + 4);

        // partial projections from carried s
        float part[8];
        #pragma unroll
        for (int r = 0; r < 8; ++r) part[r] = 0.0f;
        #pragma unroll
        for (int j = 0; j < 8; ++j) {
            #pragma unroll
            for (int r = 0; r < 8; ++r) part[r] = fmaf(s[j], nm[j][r], part[r]);
        }
        #pragma unroll
        for (int r = 0; r < 8; ++r) part[r] = wave_reduce_to_lane63(part[r]);

        if (lane == 63) {
            #pragma unroll
            for (int r = 0; r < 8; ++r) wlds[buf][r * 8 + wv] = part[r];
        }

        // decay + input (independent of proj) before the barrier
        float xd[8];
        #pragma unroll
        for (int j = 0; j < 8; ++j) xd[j] = fmaf(0.9f, x[j], uv[j]);

        __syncthreads();

        // fold 8 wave-partials per r: one ds_read + 3 DPP row_shr adds.
        float v = wlds[buf][lane];
        v = dpp_add<0x111, 0xf>(v);  // row_shr:1
        v = dpp_add<0x112, 0xf>(v);  // row_shr:2
        v = dpp_add<0x114, 0xf>(v);  // row_shr:4

        float ps[8];
        #pragma unroll
        for (int r = 0; r < 8; ++r)
            ps[r] = __int_as_float(__builtin_amdgcn_readlane(__float_as_int(v), r * 8 + 7));

        float* xrow = xseq + ((size_t)b * (TSTEPS + 1) + (t0 + tl + 1)) * NDIM + j0;
        #pragma unroll
        for (int j = 0; j < 8; ++j) {
            float acc = xd[j];
            #pragma unroll
            for (int r = 0; r < 8; ++r) acc = fmaf(ps[r], mmr[j][r], acc);
            x[j] = acc;
        }
        *(float4*)(xrow + 0) = make_float4(x[0], x[1], x[2], x[3]);
        *(float4*)(xrow + 4) = make_float4(x[4], x[5], x[6], x[7]);

        // next-step sigmoid, also emitted as bf16 for y_gemm
        #pragma unroll
        for (int j = 0; j < 8; ++j) s[j] = fast_sigmoid(x[j]);
        v8s sv;
        sv[0] = f2bf(s[0]); sv[1] = f2bf(s[1]); sv[2] = f2bf(s[2]); sv[3] = f2bf(s[3]);
        sv[4] = f2bf(s[4]); sv[5] = f2bf(s[5]); sv[6] = f2bf(s[6]); sv[7] = f2bf(s[7]);
        *(v8s*)(sbuf + ((size_t)b * tc + tl) * NDIM + j0) = sv;

        uv[0] = pf0.x; uv[1] = pf0.y; uv[2] = pf0.z; uv[3] = pf0.w;
        uv[4] = pf1.x; uv[5] = pf1.y; uv[6] = pf1.z; uv[7] = pf1.w;
    }

    float* xs = xstate + (size_t)b * NDIM + j0;
    *(float4*)(xs + 0) = make_float4(x[0], x[1], x[2], x[3]);
    *(float4*)(xs + 4) = make_float4(x[4], x[5], x[6], x[7]);
}

// ---------------------------------------------------------------------------
// Phase 3: y = s @ W^T via bf16 MFMA 16x16x32, pure loads + MFMA.
// A rows come from sbuf (chunk-local [b][tl][n], bf16); W pre-converted bf16.
// A[m][k]: m=lane&15, k=(lane>>4)*8+j  -> contiguous 8 bf16 per lane.
// B[k][o]=W[o][k]: o=lane&15, same k   -> contiguous 8 bf16 per lane.
// D: col=lane&15, row=(lane>>4)*4+reg.
// ---------------------------------------------------------------------------
__global__ __launch_bounds__(256) void y_gemm(const unsigned short* __restrict__ sbuf,
                                              const unsigned short* __restrict__ Wb,
                                              float* __restrict__ yout,
                                              int t0, int tc) {
    const int tid  = threadIdx.x;
    const int lane = tid & 63;
    const int mt   = blockIdx.x * 4 + (tid >> 6);   // m-tile index, 16 rows each
    const int lm   = lane & 15;
    const int kq   = lane >> 4;                     // 0..3

    const int tilesPerB = tc >> 4;
    const int b  = mt / tilesPerB;
    const int tt = mt % tilesPerB;

    const unsigned short* pa = sbuf + ((size_t)b * tc + tt * 16 + lm) * NDIM + kq * 8;
    const unsigned short* pw = Wb + (size_t)lm * NDIM + kq * 8;

    v4f acc[4];
    #pragma unroll
    for (int ot = 0; ot < 4; ++ot) acc[ot] = (v4f){0.f, 0.f, 0.f, 0.f};

    #pragma unroll 4
    for (int kc = 0; kc < NDIM; kc += 32) {
        v8s af = *(const v8s*)(pa + kc);
        #pragma unroll
        for (int ot = 0; ot < 4; ++ot) {
            v8s bf = *(const v8s*)(pw + (size_t)ot * 16 * NDIM + kc);
            acc[ot] = __builtin_amdgcn_mfma_f32_16x16x32_bf16(af, bf, acc[ot], 0, 0, 0);
        }
    }

    #pragma unroll
    for (int ot = 0; ot < 4; ++ot) {
        #pragma unroll
        for (int r = 0; r < 4; ++r) {
            const int row = b * TSTEPS + t0 + tt * 16 + kq * 4 + r;
            yout[(size_t)row * ODIM + ot * 16 + lm] = acc[ot][r];
        }
    }
}

extern "C" void kernel_launch(void* const* d_in, const int* in_sizes, int n_in,
                              void* d_out, int out_size, void* d_ws, size_t ws_size,
                              hipStream_t stream) {
    const float* inp = (const float*)d_in[0];   // [32][512][64]
    const float* Bm  = (const float*)d_in[1];   // [4096][64]
    const float* Wm  = (const float*)d_in[2];   // [64][4096]
    const float* mm  = (const float*)d_in[3];   // [4096][8]
    const float* nm  = (const float*)d_in[4];   // [4096][8]

    float* out  = (float*)d_out;
    float* xseq = out;                                          // [32][513][4096]
    float* yout = out + (size_t)BTRIALS * (TSTEPS + 1) * NDIM;  // [32][512][64]

    // workspace layout: xstate (512KB) | Wb (512KB) | ubuf fp32 | sbuf bf16
    float* xstate = (float*)d_ws;                               // [32][4096]
    unsigned short* Wb = (unsigned short*)(xstate + (size_t)BTRIALS * NDIM);
    const size_t head = (size_t)BTRIALS * NDIM * sizeof(float)
                      + (size_t)ODIM * NDIM * sizeof(unsigned short);
    float* ubuf = (float*)((char*)d_ws + head);

    const size_t perstep = (size_t)BTRIALS * NDIM * (sizeof(float) + sizeof(unsigned short));
    size_t avail = (ws_size > head) ? (ws_size - head) : 0;
    int Tc = (int)(avail / perstep);
    if (Tc > TSTEPS) Tc = TSTEPS;
    Tc &= ~15;                      // multiple of 16 for y_gemm tiling
    if (Tc < 16) Tc = 16;

    wconv<<<(ODIM * NDIM) / (256 * 8), 256, 0, stream>>>(Wm, Wb);

    for (int t0 = 0; t0 < TSTEPS; t0 += Tc) {
        const int tc = (TSTEPS - t0 < Tc) ? (TSTEPS - t0) : Tc;
        unsigned short* sbuf = (unsigned short*)(ubuf + (size_t)tc * BTRIALS * NDIM);
        const int rows = tc * BTRIALS;
        dim3 g1((rows + 63) / 64, NDIM / 64);
        pre_gemm<<<g1, 256, 0, stream>>>(inp, Bm, ubuf, t0, rows);
        scan_kernel<<<BTRIALS, 512, 0, stream>>>(mm, nm, ubuf, xseq, xstate, sbuf, t0, tc);
        const int mtiles = BTRIALS * (tc / 16);
        y_gemm<<<mtiles / 4, 256, 0, stream>>>(sbuf, Wb, yout, t0, tc);
    }
}